// Round 1
// baseline (182.625 us; speedup 1.0000x reference)
//
#include <hip/hip_runtime.h>
#include <hip/hip_bf16.h>

#define DM   1024
#define DH   128
#define DL   64
#define NTOK 8192
#define NEXP 65536
#define HK   32

__device__ __forceinline__ float gelu_sig(float v) {
    return v / (1.0f + __expf(-1.702f * v));
}

// ---------------- Kernel A: x_proj = x @ W_u  [8192,1024]x[1024,128] ----------------
__global__ __launch_bounds__(256) void k_xproj(const float* __restrict__ x,
                                               const float* __restrict__ Wu,
                                               float* __restrict__ xproj) {
    __shared__ float xs[32][128];
    const int t = threadIdx.x;
    const int row0 = blockIdx.x * 32;
    const int cg = t & 31;        // 32 col-groups * 4 cols = 128
    const int rg = t >> 5;        // 8 row-groups * 4 rows = 32
    float acc[4][4] = {};
    for (int kc = 0; kc < DM; kc += 128) {
        #pragma unroll
        for (int j = 0; j < 4; ++j) {
            int p = t + j * 256;          // float4 index within 32x128 tile
            int r = p >> 5, q = p & 31;
            *(float4*)&xs[r][q * 4] =
                *(const float4*)&x[(size_t)(row0 + r) * DM + kc + q * 4];
        }
        __syncthreads();
        #pragma unroll 2
        for (int k4 = 0; k4 < 32; ++k4) {
            float xk[4][4];   // [r][kk]
            #pragma unroll
            for (int r = 0; r < 4; ++r)
                *(float4*)xk[r] = *(float4*)&xs[rg * 4 + r][k4 * 4];
            float wk[4][4];   // [kk][c]
            #pragma unroll
            for (int kk = 0; kk < 4; ++kk)
                *(float4*)wk[kk] =
                    *(const float4*)&Wu[(size_t)(kc + k4 * 4 + kk) * DH + cg * 4];
            #pragma unroll
            for (int r = 0; r < 4; ++r)
                #pragma unroll
                for (int kk = 0; kk < 4; ++kk)
                    #pragma unroll
                    for (int c = 0; c < 4; ++c)
                        acc[r][c] = fmaf(xk[r][kk], wk[kk][c], acc[r][c]);
        }
        __syncthreads();
    }
    #pragma unroll
    for (int r = 0; r < 4; ++r)
        *(float4*)&xproj[(size_t)(row0 + rg * 4 + r) * DH + cg * 4] = *(float4*)acc[r];
}

// ---------------- Kernel B: H_all = gelu(E @ W1)  [65536,64]x[64,128] ----------------
__global__ __launch_bounds__(256) void k_hall(const float* __restrict__ lat,
                                              const float* __restrict__ W1,
                                              float* __restrict__ Hall) {
    __shared__ float w1s[64][128];
    __shared__ float lats[64][68];   // pad 68: conflict-free scalar reads
    const int t = threadIdx.x;
    const int e0 = blockIdx.x * 64;
    #pragma unroll
    for (int j = 0; j < 8; ++j) {            // stage W1 (8192 floats)
        int p = t + j * 256;
        *(float4*)&w1s[p >> 5][(p & 31) * 4] = *(const float4*)&W1[p * 4];
    }
    #pragma unroll
    for (int j = 0; j < 4; ++j) {            // stage 64 expert latents
        int p = t + j * 256;                 // 1024 float4s
        int e = p >> 4, l4 = p & 15;
        *(float4*)&lats[e][l4 * 4] =
            *(const float4*)&lat[(size_t)(e0 + e) * DL + l4 * 4];
    }
    __syncthreads();
    const int cg = t & 15;    // cols: cg*4..+3 and 64+cg*4..+3
    const int eg = t >> 4;    // 16 groups * 4 experts = 64
    float acc[4][8] = {};
    #pragma unroll 2
    for (int l = 0; l < DL; ++l) {
        float4 wa = *(float4*)&w1s[l][cg * 4];
        float4 wb = *(float4*)&w1s[l][64 + cg * 4];
        #pragma unroll
        for (int i = 0; i < 4; ++i) {
            float a = lats[eg * 4 + i][l];
            acc[i][0] = fmaf(a, wa.x, acc[i][0]);
            acc[i][1] = fmaf(a, wa.y, acc[i][1]);
            acc[i][2] = fmaf(a, wa.z, acc[i][2]);
            acc[i][3] = fmaf(a, wa.w, acc[i][3]);
            acc[i][4] = fmaf(a, wb.x, acc[i][4]);
            acc[i][5] = fmaf(a, wb.y, acc[i][5]);
            acc[i][6] = fmaf(a, wb.z, acc[i][6]);
            acc[i][7] = fmaf(a, wb.w, acc[i][7]);
        }
    }
    #pragma unroll
    for (int i = 0; i < 4; ++i) {
        float o[8];
        #pragma unroll
        for (int j = 0; j < 8; ++j) o[j] = gelu_sig(acc[i][j]);
        size_t e = (size_t)(e0 + eg * 4 + i);
        *(float4*)&Hall[e * DH + cg * 4]      = *(float4*)&o[0];
        *(float4*)&Hall[e * DH + 64 + cg * 4] = *(float4*)&o[4];
    }
}

// ---------------- Kernel C: gather + dot + act + accumulate ----------------
template <bool PRECOMP>
__global__ __launch_bounds__(256) void k_gather(const float* __restrict__ xproj,
                                                const float* __restrict__ scores,
                                                const int* __restrict__ idx,
                                                const float* __restrict__ HallOrLat,
                                                const float* __restrict__ W1,
                                                float* __restrict__ accout) {
    __shared__ float Hs[HK][DH];
    __shared__ float xp[DH];
    __shared__ float acts[HK];
    __shared__ int   sidx[HK];
    const int n = blockIdx.x;
    const int t = threadIdx.x;
    if (t < 128) xp[t] = xproj[(size_t)n * DH + t];
    if (t >= 224) sidx[t - 224] = idx[n * HK + (t - 224)];
    __syncthreads();
    if constexpr (PRECOMP) {
        #pragma unroll
        for (int j = 0; j < 4; ++j) {
            int p = t + j * 256;          // 1024 float4s = 32x128
            int s = p >> 5, q = p & 31;
            *(float4*)&Hs[s][q * 4] =
                *(const float4*)&HallOrLat[(size_t)sidx[s] * DH + q * 4];
        }
    } else {
        __shared__ float ls[HK][68];
        #pragma unroll
        for (int j = 0; j < 2; ++j) {     // 512 float4s = 32x64
            int p = t + j * 256;
            int s = p >> 4, l4 = p & 15;
            *(float4*)&ls[s][l4 * 4] =
                *(const float4*)&HallOrLat[(size_t)sidx[s] * DL + l4 * 4];
        }
        __syncthreads();
        const int s = t >> 3;             // 32 sels * 8 threads
        const int c0 = (t & 7) * 16;
        float h[16] = {};
        for (int l = 0; l < DL; ++l) {
            float a = ls[s][l];
            #pragma unroll
            for (int cc = 0; cc < 4; ++cc) {
                float4 w = *(const float4*)&W1[(size_t)l * DH + c0 + cc * 4];
                h[cc*4+0] = fmaf(a, w.x, h[cc*4+0]);
                h[cc*4+1] = fmaf(a, w.y, h[cc*4+1]);
                h[cc*4+2] = fmaf(a, w.z, h[cc*4+2]);
                h[cc*4+3] = fmaf(a, w.w, h[cc*4+3]);
            }
        }
        #pragma unroll
        for (int c = 0; c < 16; ++c) Hs[s][c0 + c] = gelu_sig(h[c]);
    }
    __syncthreads();
    // dots: wave w handles selections w*8..w*8+7
    const int w = t >> 6, lane = t & 63;
    for (int j = 0; j < 8; ++j) {
        int s = w * 8 + j;
        float2 hv = *(float2*)&Hs[s][lane * 2];
        float2 xv = *(float2*)&xp[lane * 2];
        float part = hv.x * xv.x + hv.y * xv.y;
        #pragma unroll
        for (int off = 32; off; off >>= 1) part += __shfl_xor(part, off, 64);
        if (lane == 0)
            acts[s] = gelu_sig(part) * scores[n * HK + s];
    }
    __syncthreads();
    if (t < 128) {
        float a = 0.0f;
        #pragma unroll
        for (int s = 0; s < HK; ++s) a = fmaf(acts[s], Hs[s][t], a);
        accout[(size_t)n * DH + t] = a;
    }
}

// ---------------- Kernel D: out = (acc @ W_v) / 4  [8192,128]x[128,1024] ----------------
__global__ __launch_bounds__(256) void k_out(const float* __restrict__ acc,
                                             const float* __restrict__ Wv,
                                             float* __restrict__ out) {
    __shared__ float as[16][128];
    const int t = threadIdx.x;
    const int row0 = blockIdx.x * 16;
    const int c0 = blockIdx.y * 256;
    #pragma unroll
    for (int j = 0; j < 2; ++j) {
        int p = t + j * 256;              // 512 float4s = 16x128
        int r = p >> 5, q = p & 31;
        *(float4*)&as[r][q * 4] =
            *(const float4*)&acc[(size_t)(row0 + r) * DH + q * 4];
    }
    __syncthreads();
    const int cg = t & 63;   // 64 col-groups * 4 = 256 cols
    const int rg = t >> 6;   // 4 row-groups * 4 = 16 rows
    float o[4][4] = {};
    #pragma unroll 2
    for (int f4 = 0; f4 < 32; ++f4) {
        float xk[4][4];  // [r][ff]
        #pragma unroll
        for (int r = 0; r < 4; ++r)
            *(float4*)xk[r] = *(float4*)&as[rg * 4 + r][f4 * 4];
        #pragma unroll
        for (int ff = 0; ff < 4; ++ff) {
            float4 wv = *(const float4*)&Wv[(size_t)(f4 * 4 + ff) * DM + c0 + cg * 4];
            #pragma unroll
            for (int r = 0; r < 4; ++r) {
                o[r][0] = fmaf(xk[r][ff], wv.x, o[r][0]);
                o[r][1] = fmaf(xk[r][ff], wv.y, o[r][1]);
                o[r][2] = fmaf(xk[r][ff], wv.z, o[r][2]);
                o[r][3] = fmaf(xk[r][ff], wv.w, o[r][3]);
            }
        }
    }
    #pragma unroll
    for (int r = 0; r < 4; ++r) {
        float4 v;
        v.x = o[r][0] * 0.25f; v.y = o[r][1] * 0.25f;
        v.z = o[r][2] * 0.25f; v.w = o[r][3] * 0.25f;
        *(float4*)&out[(size_t)(row0 + rg * 4 + r) * DM + c0 + cg * 4] = v;
    }
}

extern "C" void kernel_launch(void* const* d_in, const int* in_sizes, int n_in,
                              void* d_out, int out_size, void* d_ws, size_t ws_size,
                              hipStream_t stream) {
    const float* x      = (const float*)d_in[0];
    const float* scores = (const float*)d_in[1];
    const int*   idx    = (const int*)d_in[2];
    const float* lat    = (const float*)d_in[3];
    const float* W1     = (const float*)d_in[4];
    const float* Wu     = (const float*)d_in[5];
    const float* Wv     = (const float*)d_in[6];
    float* out = (float*)d_out;

    float* xproj  = (float*)d_ws;                       // 8192*128
    float* accbuf = xproj + (size_t)NTOK * DH;          // 8192*128
    float* Hall   = accbuf + (size_t)NTOK * DH;         // 65536*128
    const size_t need = ((size_t)NTOK * DH * 2 + (size_t)NEXP * DH) * sizeof(float);
    const bool precomp = ws_size >= need;

    k_xproj<<<NTOK / 32, 256, 0, stream>>>(x, Wu, xproj);
    if (precomp) {
        k_hall<<<NEXP / 64, 256, 0, stream>>>(lat, W1, Hall);
        k_gather<true><<<NTOK, 256, 0, stream>>>(xproj, scores, idx, Hall, W1, accbuf);
    } else {
        k_gather<false><<<NTOK, 256, 0, stream>>>(xproj, scores, idx, lat, W1, accbuf);
    }
    k_out<<<dim3(NTOK / 16, DM / 256), 256, 0, stream>>>(accbuf, Wv, out);
}

// Round 2
// 148.411 us; speedup vs baseline: 1.2305x; 1.2305x over previous
//
#include <hip/hip_runtime.h>
#include <hip/hip_bf16.h>

#define DM   1024
#define DH   128
#define DL   64
#define NTOK 8192
#define NEXP 65536
#define HK   32
#define KSPLIT 4

__device__ __forceinline__ float gelu_sig(float v) {
    return v / (1.0f + __expf(-1.702f * v));
}

// ---------------- Kernel A: x_proj partials = x @ W_u  (split-K) ----------------
// grid (NTOK/32, KSPLIT); each block: 32 rows x 128 cols over K range of 256.
__global__ __launch_bounds__(256) void k_xproj(const float* __restrict__ x,
                                               const float* __restrict__ Wu,
                                               float* __restrict__ xpart) {
    __shared__ float xs[32][128];
    const int t = threadIdx.x;
    const int row0 = blockIdx.x * 32;
    const int ks = blockIdx.y;
    const int k0 = ks * (DM / KSPLIT);
    const int cg = t & 31;        // 32 col-groups * 4 cols = 128
    const int rg = t >> 5;        // 8 row-groups * 4 rows = 32
    float acc[4][4] = {};
    for (int kc = k0; kc < k0 + DM / KSPLIT; kc += 128) {
        #pragma unroll
        for (int j = 0; j < 4; ++j) {
            int p = t + j * 256;          // float4 index within 32x128 tile
            int r = p >> 5, q = p & 31;
            *(float4*)&xs[r][q * 4] =
                *(const float4*)&x[(size_t)(row0 + r) * DM + kc + q * 4];
        }
        __syncthreads();
        #pragma unroll 2
        for (int k4 = 0; k4 < 32; ++k4) {
            float xk[4][4];   // [r][kk]
            #pragma unroll
            for (int r = 0; r < 4; ++r)
                *(float4*)xk[r] = *(float4*)&xs[rg * 4 + r][k4 * 4];
            float wk[4][4];   // [kk][c]
            #pragma unroll
            for (int kk = 0; kk < 4; ++kk)
                *(float4*)wk[kk] =
                    *(const float4*)&Wu[(size_t)(kc + k4 * 4 + kk) * DH + cg * 4];
            #pragma unroll
            for (int r = 0; r < 4; ++r)
                #pragma unroll
                for (int kk = 0; kk < 4; ++kk)
                    #pragma unroll
                    for (int c = 0; c < 4; ++c)
                        acc[r][c] = fmaf(xk[r][kk], wk[kk][c], acc[r][c]);
        }
        __syncthreads();
    }
    float* dst = xpart + (size_t)ks * NTOK * DH;
    #pragma unroll
    for (int r = 0; r < 4; ++r)
        *(float4*)&dst[(size_t)(row0 + rg * 4 + r) * DH + cg * 4] = *(float4*)acc[r];
}

// ---------------- Kernel A2: xproj = sum of KSPLIT partials ----------------
__global__ __launch_bounds__(256) void k_xreduce(const float* __restrict__ xpart,
                                                 float* __restrict__ xproj) {
    const size_t i = ((size_t)blockIdx.x * 256 + threadIdx.x) * 4;
    float4 a = *(const float4*)&xpart[i];
    #pragma unroll
    for (int s = 1; s < KSPLIT; ++s) {
        float4 b = *(const float4*)&xpart[(size_t)s * NTOK * DH + i];
        a.x += b.x; a.y += b.y; a.z += b.z; a.w += b.w;
    }
    *(float4*)&xproj[i] = a;
}

// ---------------- Kernel B: H_all = gelu(E @ W1)  [65536,64]x[64,128] ----------------
__global__ __launch_bounds__(256) void k_hall(const float* __restrict__ lat,
                                              const float* __restrict__ W1,
                                              float* __restrict__ Hall) {
    __shared__ float w1s[64][128];
    __shared__ float lats[64][65];
    const int t = threadIdx.x;
    const int e0 = blockIdx.x * 64;
    #pragma unroll
    for (int j = 0; j < 8; ++j) {            // stage W1 (8192 floats)
        int p = t + j * 256;
        *(float4*)&w1s[p >> 5][(p & 31) * 4] = *(const float4*)&W1[p * 4];
    }
    #pragma unroll
    for (int j = 0; j < 4; ++j) {            // stage 64 expert latents
        int p = t + j * 256;                 // 1024 float4s
        int e = p >> 4, l4 = p & 15;
        float4 v = *(const float4*)&lat[(size_t)(e0 + e) * DL + l4 * 4];
        lats[e][l4 * 4 + 0] = v.x;
        lats[e][l4 * 4 + 1] = v.y;
        lats[e][l4 * 4 + 2] = v.z;
        lats[e][l4 * 4 + 3] = v.w;
    }
    __syncthreads();
    const int cg = t & 15;    // cols: cg*4..+3 and 64+cg*4..+3
    const int eg = t >> 4;    // 16 groups * 4 experts = 64
    float acc[4][8] = {};
    #pragma unroll 2
    for (int l = 0; l < DL; ++l) {
        float4 wa = *(float4*)&w1s[l][cg * 4];
        float4 wb = *(float4*)&w1s[l][64 + cg * 4];
        #pragma unroll
        for (int i = 0; i < 4; ++i) {
            float a = lats[eg * 4 + i][l];
            acc[i][0] = fmaf(a, wa.x, acc[i][0]);
            acc[i][1] = fmaf(a, wa.y, acc[i][1]);
            acc[i][2] = fmaf(a, wa.z, acc[i][2]);
            acc[i][3] = fmaf(a, wa.w, acc[i][3]);
            acc[i][4] = fmaf(a, wb.x, acc[i][4]);
            acc[i][5] = fmaf(a, wb.y, acc[i][5]);
            acc[i][6] = fmaf(a, wb.z, acc[i][6]);
            acc[i][7] = fmaf(a, wb.w, acc[i][7]);
        }
    }
    #pragma unroll
    for (int i = 0; i < 4; ++i) {
        float o[8];
        #pragma unroll
        for (int j = 0; j < 8; ++j) o[j] = gelu_sig(acc[i][j]);
        size_t e = (size_t)(e0 + eg * 4 + i);
        *(float4*)&Hall[e * DH + cg * 4]      = *(float4*)&o[0];
        *(float4*)&Hall[e * DH + 64 + cg * 4] = *(float4*)&o[4];
    }
}

// ---------------- Kernel C: gather + dot + act + accumulate ----------------
__global__ __launch_bounds__(256) void k_gather(const float* __restrict__ xproj,
                                                const float* __restrict__ scores,
                                                const int* __restrict__ idx,
                                                const float* __restrict__ Hall,
                                                float* __restrict__ accout) {
    __shared__ float Hs[HK][DH];
    __shared__ float xp[DH];
    __shared__ float acts[HK];
    __shared__ int   sidx[HK];
    const int n = blockIdx.x;
    const int t = threadIdx.x;
    if (t < 128) xp[t] = xproj[(size_t)n * DH + t];
    if (t >= 224) sidx[t - 224] = idx[n * HK + (t - 224)];
    __syncthreads();
    #pragma unroll
    for (int j = 0; j < 4; ++j) {
        int p = t + j * 256;          // 1024 float4s = 32x128
        int s = p >> 5, q = p & 31;
        *(float4*)&Hs[s][q * 4] =
            *(const float4*)&Hall[(size_t)sidx[s] * DH + q * 4];
    }
    __syncthreads();
    // dots: wave w handles selections w*8..w*8+7
    const int w = t >> 6, lane = t & 63;
    for (int j = 0; j < 8; ++j) {
        int s = w * 8 + j;
        float2 hv = *(float2*)&Hs[s][lane * 2];
        float2 xv = *(float2*)&xp[lane * 2];
        float part = hv.x * xv.x + hv.y * xv.y;
        #pragma unroll
        for (int off = 32; off; off >>= 1) part += __shfl_xor(part, off, 64);
        if (lane == 0)
            acts[s] = gelu_sig(part) * scores[n * HK + s];
    }
    __syncthreads();
    if (t < 128) {
        float a = 0.0f;
        #pragma unroll
        for (int s = 0; s < HK; ++s) a = fmaf(acts[s], Hs[s][t], a);
        accout[(size_t)n * DH + t] = a;
    }
}

// ---------------- Kernel D: out = (acc @ W_v) / 4  [8192,128]x[128,1024] ----------------
__global__ __launch_bounds__(256) void k_out(const float* __restrict__ acc,
                                             const float* __restrict__ Wv,
                                             float* __restrict__ out) {
    __shared__ float as[16][128];
    const int t = threadIdx.x;
    const int row0 = blockIdx.x * 16;
    const int c0 = blockIdx.y * 256;
    #pragma unroll
    for (int j = 0; j < 2; ++j) {
        int p = t + j * 256;              // 512 float4s = 16x128
        int r = p >> 5, q = p & 31;
        *(float4*)&as[r][q * 4] =
            *(const float4*)&acc[(size_t)(row0 + r) * DH + q * 4];
    }
    __syncthreads();
    const int cg = t & 63;   // 64 col-groups * 4 = 256 cols
    const int rg = t >> 6;   // 4 row-groups * 4 = 16 rows
    float o[4][4] = {};
    #pragma unroll 2
    for (int f4 = 0; f4 < 32; ++f4) {
        float xk[4][4];  // [r][ff]
        #pragma unroll
        for (int r = 0; r < 4; ++r)
            *(float4*)xk[r] = *(float4*)&as[rg * 4 + r][f4 * 4];
        #pragma unroll
        for (int ff = 0; ff < 4; ++ff) {
            float4 wv = *(const float4*)&Wv[(size_t)(f4 * 4 + ff) * DM + c0 + cg * 4];
            #pragma unroll
            for (int r = 0; r < 4; ++r) {
                o[r][0] = fmaf(xk[r][ff], wv.x, o[r][0]);
                o[r][1] = fmaf(xk[r][ff], wv.y, o[r][1]);
                o[r][2] = fmaf(xk[r][ff], wv.z, o[r][2]);
                o[r][3] = fmaf(xk[r][ff], wv.w, o[r][3]);
            }
        }
    }
    #pragma unroll
    for (int r = 0; r < 4; ++r) {
        float4 v;
        v.x = o[r][0] * 0.25f; v.y = o[r][1] * 0.25f;
        v.z = o[r][2] * 0.25f; v.w = o[r][3] * 0.25f;
        *(float4*)&out[(size_t)(row0 + rg * 4 + r) * DM + c0 + cg * 4] = v;
    }
}

extern "C" void kernel_launch(void* const* d_in, const int* in_sizes, int n_in,
                              void* d_out, int out_size, void* d_ws, size_t ws_size,
                              hipStream_t stream) {
    const float* x      = (const float*)d_in[0];
    const float* scores = (const float*)d_in[1];
    const int*   idx    = (const int*)d_in[2];
    const float* lat    = (const float*)d_in[3];
    const float* W1     = (const float*)d_in[4];
    const float* Wu     = (const float*)d_in[5];
    const float* Wv     = (const float*)d_in[6];
    float* out = (float*)d_out;

    float* xproj  = (float*)d_ws;                       // 8192*128
    float* accbuf = xproj + (size_t)NTOK * DH;          // 8192*128
    float* Hall   = accbuf + (size_t)NTOK * DH;         // 65536*128
    // split-K partials live in the Hall region (Hall written strictly later)
    float* xpart  = Hall;                               // KSPLIT * 8192*128

    k_xproj<<<dim3(NTOK / 32, KSPLIT), 256, 0, stream>>>(x, Wu, xpart);
    k_xreduce<<<(NTOK * DH / 4) / 256, 256, 0, stream>>>(xpart, xproj);
    k_hall<<<NEXP / 64, 256, 0, stream>>>(lat, W1, Hall);
    k_gather<<<NTOK, 256, 0, stream>>>(xproj, scores, idx, Hall, accbuf);
    k_out<<<dim3(NTOK / 16, DM / 256), 256, 0, stream>>>(accbuf, Wv, out);
}

// Round 4
// 83.001 us; speedup vs baseline: 2.2003x; 1.7881x over previous
//
#include <hip/hip_runtime.h>
#include <hip/hip_bf16.h>

#define DM   1024
#define DH   128
#define DL   64
#define NTOK 8192
#define NEXP 65536
#define HK   32

typedef __attribute__((ext_vector_type(4))) float f32x4;
typedef __attribute__((ext_vector_type(8))) short bf16x8;

__device__ __forceinline__ float gelu_sig(float v) {
    return v / (1.0f + __expf(-1.702f * v));
}

__device__ __forceinline__ unsigned short f2bf(float f) {
    union { float f; unsigned u; } v; v.f = f;
    unsigned r = v.u + 0x7FFFu + ((v.u >> 16) & 1u);   // RNE
    return (unsigned short)(r >> 16);
}

__device__ __forceinline__ bf16x8 pack8(const float4& a, const float4& b) {
    bf16x8 r;
    r[0] = (short)f2bf(a.x); r[1] = (short)f2bf(a.y);
    r[2] = (short)f2bf(a.z); r[3] = (short)f2bf(a.w);
    r[4] = (short)f2bf(b.x); r[5] = (short)f2bf(b.y);
    r[6] = (short)f2bf(b.z); r[7] = (short)f2bf(b.w);
    return r;
}

// ---------------- Kernel P: Wut[c][k] = bf16(Wu[k][c])  (128 x 1024) ----------------
__global__ __launch_bounds__(256) void k_prep(const float* __restrict__ Wu,
                                              unsigned short* __restrict__ Wut) {
    const int i = blockIdx.x * 256 + threadIdx.x;   // 131072 total
    const int c = i >> 10, k = i & 1023;
    Wut[i] = f2bf(Wu[k * DH + c]);
}

// ---------------- Kernel A: xproj = x @ Wu via bf16 MFMA ----------------
// BM=32, N=128, BK=64; 4 waves; wave w -> cols w*32 (N_rep=2), M_rep=2.
__global__ __launch_bounds__(256) void k_xproj(const float* __restrict__ x,
                                               const unsigned short* __restrict__ Wut,
                                               float* __restrict__ xproj) {
    __shared__ unsigned short As[32][72];    // 32 rows x 64 k (+8 pad)
    __shared__ unsigned short Bs[128][72];   // 128 cols x 64 k (+8 pad)
    const int t = threadIdx.x;
    const int w = t >> 6, l = t & 63;
    const int fr = l & 15, fh = l >> 4;      // frag row/col, k-base = fh*8
    const int row0 = blockIdx.x * 32;
    // staging maps
    const int ar = t >> 3, ac = (t & 7) * 8;     // A: 8 floats per thread (32x64 total)
    const int bc = t >> 1, bk = (t & 1) * 32;    // B: 32 bf16 per thread (128x64 total)

    f32x4 acc[2][2] = {};                    // [m][n]
    float4 a0, a1; bf16x8 b0, b1, b2, b3;

    // prologue: tile 0 into regs
    a0 = *(const float4*)&x[(size_t)(row0 + ar) * DM + ac];
    a1 = *(const float4*)&x[(size_t)(row0 + ar) * DM + ac + 4];
    b0 = *(const bf16x8*)&Wut[(size_t)bc * DM + bk];
    b1 = *(const bf16x8*)&Wut[(size_t)bc * DM + bk + 8];
    b2 = *(const bf16x8*)&Wut[(size_t)bc * DM + bk + 16];
    b3 = *(const bf16x8*)&Wut[(size_t)bc * DM + bk + 24];

    for (int it = 0; it < DM / 64; ++it) {
        if (it) __syncthreads();             // previous compute done
        *(bf16x8*)&As[ar][ac]      = pack8(a0, a1);
        *(bf16x8*)&Bs[bc][bk]      = b0;
        *(bf16x8*)&Bs[bc][bk + 8]  = b1;
        *(bf16x8*)&Bs[bc][bk + 16] = b2;
        *(bf16x8*)&Bs[bc][bk + 24] = b3;
        __syncthreads();
        if (it < DM / 64 - 1) {
            const int kc = (it + 1) * 64;
            a0 = *(const float4*)&x[(size_t)(row0 + ar) * DM + kc + ac];
            a1 = *(const float4*)&x[(size_t)(row0 + ar) * DM + kc + ac + 4];
            b0 = *(const bf16x8*)&Wut[(size_t)bc * DM + kc + bk];
            b1 = *(const bf16x8*)&Wut[(size_t)bc * DM + kc + bk + 8];
            b2 = *(const bf16x8*)&Wut[(size_t)bc * DM + kc + bk + 16];
            b3 = *(const bf16x8*)&Wut[(size_t)bc * DM + kc + bk + 24];
        }
        #pragma unroll
        for (int kk = 0; kk < 2; ++kk) {
            bf16x8 bv[2];
            #pragma unroll
            for (int n = 0; n < 2; ++n)
                bv[n] = *(bf16x8*)&Bs[w * 32 + n * 16 + fr][kk * 32 + fh * 8];
            #pragma unroll
            for (int m = 0; m < 2; ++m) {
                bf16x8 av = *(bf16x8*)&As[m * 16 + fr][kk * 32 + fh * 8];
                #pragma unroll
                for (int n = 0; n < 2; ++n)
                    acc[m][n] = __builtin_amdgcn_mfma_f32_16x16x32_bf16(
                        av, bv[n], acc[m][n], 0, 0, 0);
            }
        }
    }
    #pragma unroll
    for (int m = 0; m < 2; ++m)
        #pragma unroll
        for (int n = 0; n < 2; ++n)
            #pragma unroll
            for (int r = 0; r < 4; ++r)
                xproj[(size_t)(row0 + m * 16 + fh * 4 + r) * DH + w * 32 + n * 16 + fr] =
                    acc[m][n][r];
}

// ---------------- Kernel B: Hall = gelu(lat @ W1) via bf16 MFMA ----------------
// BM=64, N=128, K=64 single-shot; 4 waves; M_rep=4, N_rep=2.
__global__ __launch_bounds__(256) void k_hall(const float* __restrict__ lat,
                                              const float* __restrict__ W1,
                                              float* __restrict__ Hall) {
    __shared__ unsigned short As[64][72];    // 64 experts x 64 latent (+8 pad)
    const int t = threadIdx.x;
    const int w = t >> 6, l = t & 63;
    const int fr = l & 15, fh = l >> 4;
    const int e0 = blockIdx.x * 64;
    const int ar = t >> 2, ac = (t & 3) * 16;    // 16 floats per thread (64x64 total)

    // stage A (fp32 -> bf16)
    {
        const float* src = &lat[(size_t)(e0 + ar) * DL + ac];
        float4 v0 = *(const float4*)&src[0],  v1 = *(const float4*)&src[4];
        float4 v2 = *(const float4*)&src[8],  v3 = *(const float4*)&src[12];
        *(bf16x8*)&As[ar][ac]     = pack8(v0, v1);
        *(bf16x8*)&As[ar][ac + 8] = pack8(v2, v3);
    }
    // B frags direct from W1 (L2-resident), col = w*32 + n*16 + fr
    bf16x8 bv[2][2];                         // [n][kk]
    #pragma unroll
    for (int n = 0; n < 2; ++n)
        #pragma unroll
        for (int kk = 0; kk < 2; ++kk)
            #pragma unroll
            for (int b = 0; b < 8; ++b)
                bv[n][kk][b] = (short)f2bf(
                    W1[(size_t)(kk * 32 + fh * 8 + b) * DH + w * 32 + n * 16 + fr]);
    __syncthreads();

    f32x4 acc[4][2] = {};
    #pragma unroll
    for (int kk = 0; kk < 2; ++kk)
        #pragma unroll
        for (int m = 0; m < 4; ++m) {
            bf16x8 av = *(bf16x8*)&As[m * 16 + fr][kk * 32 + fh * 8];
            #pragma unroll
            for (int n = 0; n < 2; ++n)
                acc[m][n] = __builtin_amdgcn_mfma_f32_16x16x32_bf16(
                    av, bv[n][kk], acc[m][n], 0, 0, 0);
        }
    #pragma unroll
    for (int m = 0; m < 4; ++m)
        #pragma unroll
        for (int n = 0; n < 2; ++n)
            #pragma unroll
            for (int r = 0; r < 4; ++r)
                Hall[(size_t)(e0 + m * 16 + fh * 4 + r) * DH + w * 32 + n * 16 + fr] =
                    gelu_sig(acc[m][n][r]);
}

// ---------------- Kernel C: gather + dot + act + accumulate (fp32) ----------------
__global__ __launch_bounds__(256) void k_gather(const float* __restrict__ xproj,
                                                const float* __restrict__ scores,
                                                const int* __restrict__ idx,
                                                const float* __restrict__ Hall,
                                                float* __restrict__ accout) {
    __shared__ float Hs[HK][DH];
    __shared__ float xp[DH];
    __shared__ float acts[HK];
    __shared__ int   sidx[HK];
    const int n = blockIdx.x;
    const int t = threadIdx.x;
    if (t < 128) xp[t] = xproj[(size_t)n * DH + t];
    if (t >= 224) sidx[t - 224] = idx[n * HK + (t - 224)];
    __syncthreads();
    #pragma unroll
    for (int j = 0; j < 4; ++j) {
        int p = t + j * 256;          // 1024 float4s = 32x128
        int s = p >> 5, q = p & 31;
        *(float4*)&Hs[s][q * 4] =
            *(const float4*)&Hall[(size_t)sidx[s] * DH + q * 4];
    }
    __syncthreads();
    const int w = t >> 6, lane = t & 63;
    for (int j = 0; j < 8; ++j) {
        int s = w * 8 + j;
        float2 hv = *(float2*)&Hs[s][lane * 2];
        float2 xv = *(float2*)&xp[lane * 2];
        float part = hv.x * xv.x + hv.y * xv.y;
        #pragma unroll
        for (int off = 32; off; off >>= 1) part += __shfl_xor(part, off, 64);
        if (lane == 0)
            acts[s] = gelu_sig(part) * scores[n * HK + s];
    }
    __syncthreads();
    if (t < 128) {
        float a = 0.0f;
        #pragma unroll
        for (int s = 0; s < HK; ++s) a = fmaf(acts[s], Hs[s][t], a);
        accout[(size_t)n * DH + t] = a;
    }
}

// ---------------- Kernel D: out = (acc @ Wv)/4 via bf16 MFMA ----------------
// BM=64, BN=128, K=128 single-shot; grid (128, 8); M_rep=4, N_rep=2.
__global__ __launch_bounds__(256) void k_out(const float* __restrict__ acc,
                                             const float* __restrict__ Wv,
                                             float* __restrict__ out) {
    __shared__ unsigned short As[64][136];   // 64 rows x 128 k (+8 pad)
    const int t = threadIdx.x;
    const int w = t >> 6, l = t & 63;
    const int fr = l & 15, fh = l >> 4;
    const int row0 = blockIdx.x * 64;
    const int c0 = blockIdx.y * 128;
    const int ar = t >> 2, ac = (t & 3) * 32;    // 32 floats per thread (64x128 total)

    // stage A (fp32 -> bf16)
    {
        const float* src = &acc[(size_t)(row0 + ar) * DH + ac];
        #pragma unroll
        for (int j = 0; j < 4; ++j) {
            float4 v0 = *(const float4*)&src[j * 8];
            float4 v1 = *(const float4*)&src[j * 8 + 4];
            *(bf16x8*)&As[ar][ac + j * 8] = pack8(v0, v1);
        }
    }
    // B frags direct from Wv (L2-resident): col = c0 + w*32 + n*16 + fr
    bf16x8 bv[2][4];                         // [n][kk]
    #pragma unroll
    for (int n = 0; n < 2; ++n)
        #pragma unroll
        for (int kk = 0; kk < 4; ++kk)
            #pragma unroll
            for (int b = 0; b < 8; ++b)
                bv[n][kk][b] = (short)f2bf(
                    Wv[(size_t)(kk * 32 + fh * 8 + b) * DM + c0 + w * 32 + n * 16 + fr]);
    __syncthreads();

    f32x4 o[4][2] = {};
    #pragma unroll
    for (int kk = 0; kk < 4; ++kk)
        #pragma unroll
        for (int m = 0; m < 4; ++m) {
            bf16x8 av = *(bf16x8*)&As[m * 16 + fr][kk * 32 + fh * 8];
            #pragma unroll
            for (int n = 0; n < 2; ++n)
                o[m][n] = __builtin_amdgcn_mfma_f32_16x16x32_bf16(
                    av, bv[n][kk], o[m][n], 0, 0, 0);
        }
    #pragma unroll
    for (int m = 0; m < 4; ++m)
        #pragma unroll
        for (int n = 0; n < 2; ++n)
            #pragma unroll
            for (int r = 0; r < 4; ++r)
                out[(size_t)(row0 + m * 16 + fh * 4 + r) * DM + c0 + w * 32 + n * 16 + fr] =
                    o[m][n][r] * 0.25f;
}

extern "C" void kernel_launch(void* const* d_in, const int* in_sizes, int n_in,
                              void* d_out, int out_size, void* d_ws, size_t ws_size,
                              hipStream_t stream) {
    const float* x      = (const float*)d_in[0];
    const float* scores = (const float*)d_in[1];
    const int*   idx    = (const int*)d_in[2];
    const float* lat    = (const float*)d_in[3];
    const float* W1     = (const float*)d_in[4];
    const float* Wu     = (const float*)d_in[5];
    const float* Wv     = (const float*)d_in[6];
    float* out = (float*)d_out;

    float* xproj  = (float*)d_ws;                       // 8192*128 f32
    float* accbuf = xproj + (size_t)NTOK * DH;          // 8192*128 f32
    float* Hall   = accbuf + (size_t)NTOK * DH;         // 65536*128 f32
    // Wut (bf16 128x1024, 256 KB) overlays accbuf: dead before k_gather writes it.
    unsigned short* Wut = (unsigned short*)accbuf;

    k_prep<<<(DH * DM) / 256, 256, 0, stream>>>(Wu, Wut);
    k_xproj<<<NTOK / 32, 256, 0, stream>>>(x, Wut, xproj);
    k_hall<<<NEXP / 64, 256, 0, stream>>>(lat, W1, Hall);
    k_gather<<<NTOK, 256, 0, stream>>>(xproj, scores, idx, Hall, accbuf);
    k_out<<<dim3(NTOK / 64, DM / 128), 256, 0, stream>>>(accbuf, Wv, out);
}

// Round 5
// 79.907 us; speedup vs baseline: 2.2855x; 1.0387x over previous
//
#include <hip/hip_runtime.h>
#include <hip/hip_bf16.h>

#define DM   1024
#define DH   128
#define DL   64
#define NTOK 8192
#define NEXP 65536
#define HK   32

typedef __attribute__((ext_vector_type(4))) float f32x4;
typedef __attribute__((ext_vector_type(8))) short bf16x8;

__device__ __forceinline__ float gelu_sig(float v) {
    return v / (1.0f + __expf(-1.702f * v));
}

__device__ __forceinline__ unsigned short f2bf(float f) {
    union { float f; unsigned u; } v; v.f = f;
    unsigned r = v.u + 0x7FFFu + ((v.u >> 16) & 1u);   // RNE
    return (unsigned short)(r >> 16);
}

__device__ __forceinline__ bf16x8 pack8(const float4& a, const float4& b) {
    bf16x8 r;
    r[0] = (short)f2bf(a.x); r[1] = (short)f2bf(a.y);
    r[2] = (short)f2bf(a.z); r[3] = (short)f2bf(a.w);
    r[4] = (short)f2bf(b.x); r[5] = (short)f2bf(b.y);
    r[6] = (short)f2bf(b.z); r[7] = (short)f2bf(b.w);
    return r;
}

// ---------------- Kernel P: transpose+convert Wu -> Wut[c][k], W1 -> W1T[c][k] ----------------
__global__ __launch_bounds__(256) void k_prep(const float* __restrict__ Wu,
                                              const float* __restrict__ W1,
                                              unsigned short* __restrict__ Wut,
                                              unsigned short* __restrict__ W1T) {
    const int b = blockIdx.x, t = threadIdx.x;
    if (b < 512) {                       // Wut: 128 x 1024
        const int i = b * 256 + t;
        const int c = i >> 10, k = i & 1023;
        Wut[i] = f2bf(Wu[k * DH + c]);
    } else {                             // W1T: 128 x 64
        const int j = (b - 512) * 256 + t;
        const int c = j >> 6, k = j & 63;
        W1T[j] = f2bf(W1[k * DH + c]);
    }
}

// ---------------- Kernel A: xproj = x @ Wu via bf16 MFMA ----------------
// grid (NTOK/32, 2): 32 rows x 64 cols per block; 4 waves, each 16 cols (N_rep=1, M_rep=2).
__global__ __launch_bounds__(256) void k_xproj(const float* __restrict__ x,
                                               const unsigned short* __restrict__ Wut,
                                               float* __restrict__ xproj) {
    __shared__ unsigned short As[32][72];    // 32 rows x 64 k (+8 pad)
    __shared__ unsigned short Bs[64][72];    // 64 cols x 64 k (+8 pad)
    const int t = threadIdx.x;
    const int w = t >> 6, l = t & 63;
    const int fr = l & 15, fh = l >> 4;
    const int row0 = blockIdx.x * 32;
    const int cb = blockIdx.y * 64;
    const int ar = t >> 3, ac = (t & 7) * 8;     // A: 8 floats/thread (32x64)
    const int bc = t >> 2, bk = (t & 3) * 16;    // B: 16 bf16/thread (64x64)

    f32x4 acc[2] = {};
    float4 a0, a1; bf16x8 b0, b1;

    a0 = *(const float4*)&x[(size_t)(row0 + ar) * DM + ac];
    a1 = *(const float4*)&x[(size_t)(row0 + ar) * DM + ac + 4];
    b0 = *(const bf16x8*)&Wut[(size_t)(cb + bc) * DM + bk];
    b1 = *(const bf16x8*)&Wut[(size_t)(cb + bc) * DM + bk + 8];

    for (int it = 0; it < DM / 64; ++it) {
        if (it) __syncthreads();
        *(bf16x8*)&As[ar][ac]     = pack8(a0, a1);
        *(bf16x8*)&Bs[bc][bk]     = b0;
        *(bf16x8*)&Bs[bc][bk + 8] = b1;
        __syncthreads();
        if (it < DM / 64 - 1) {
            const int kc = (it + 1) * 64;
            a0 = *(const float4*)&x[(size_t)(row0 + ar) * DM + kc + ac];
            a1 = *(const float4*)&x[(size_t)(row0 + ar) * DM + kc + ac + 4];
            b0 = *(const bf16x8*)&Wut[(size_t)(cb + bc) * DM + kc + bk];
            b1 = *(const bf16x8*)&Wut[(size_t)(cb + bc) * DM + kc + bk + 8];
        }
        #pragma unroll
        for (int kk = 0; kk < 2; ++kk) {
            bf16x8 bv = *(bf16x8*)&Bs[w * 16 + fr][kk * 32 + fh * 8];
            #pragma unroll
            for (int m = 0; m < 2; ++m) {
                bf16x8 av = *(bf16x8*)&As[m * 16 + fr][kk * 32 + fh * 8];
                acc[m] = __builtin_amdgcn_mfma_f32_16x16x32_bf16(av, bv, acc[m], 0, 0, 0);
            }
        }
    }
    #pragma unroll
    for (int m = 0; m < 2; ++m)
        #pragma unroll
        for (int r = 0; r < 4; ++r)
            xproj[(size_t)(row0 + m * 16 + fh * 4 + r) * DH + cb + w * 16 + fr] =
                acc[m][r];
}

// ---------------- Kernel C: gather lat + h=gelu(lat@W1) MFMA + dot + act + accumulate ----------------
__global__ __launch_bounds__(256) void k_gather(const float* __restrict__ xproj,
                                                const float* __restrict__ scores,
                                                const int* __restrict__ idx,
                                                const float* __restrict__ lat,
                                                const unsigned short* __restrict__ W1T,
                                                float* __restrict__ accout) {
    __shared__ unsigned short As[HK][72];    // 32 sel x 64 latent bf16 (+8 pad)
    __shared__ float Hs[HK][132];            // 32 sel x 128 hidden fp32 (+4 pad)
    __shared__ float xp[DH];
    __shared__ float acts[HK];
    __shared__ int   sidx[HK];
    const int n = blockIdx.x;
    const int t = threadIdx.x;
    const int w = t >> 6, l = t & 63;
    const int fr = l & 15, fh = l >> 4;

    if (t < 128) xp[t] = xproj[(size_t)n * DH + t];
    if (t >= 224) sidx[t - 224] = idx[n * HK + (t - 224)];
    __syncthreads();

    // gather lat rows -> bf16 LDS (32 x 64)
    {
        const int row = t >> 3, c = (t & 7) * 8;
        const float* src = &lat[(size_t)sidx[row] * DL + c];
        float4 v0 = *(const float4*)&src[0], v1 = *(const float4*)&src[4];
        *(bf16x8*)&As[row][c] = pack8(v0, v1);
    }
    // B fragments from W1T (16 KB, L2-hot): col = w*32 + n2*16 + fr
    bf16x8 bv[2][2];                          // [n2][kk]
    #pragma unroll
    for (int n2 = 0; n2 < 2; ++n2)
        #pragma unroll
        for (int kk = 0; kk < 2; ++kk)
            bv[n2][kk] = *(const bf16x8*)
                &W1T[(size_t)(w * 32 + n2 * 16 + fr) * DL + kk * 32 + fh * 8];
    __syncthreads();

    // h = gelu(lat @ W1): M=32, N=128, K=64; wave w -> cols w*32 (M_rep=2, N_rep=2)
    f32x4 acc[2][2] = {};
    #pragma unroll
    for (int kk = 0; kk < 2; ++kk)
        #pragma unroll
        for (int m = 0; m < 2; ++m) {
            bf16x8 av = *(bf16x8*)&As[m * 16 + fr][kk * 32 + fh * 8];
            #pragma unroll
            for (int n2 = 0; n2 < 2; ++n2)
                acc[m][n2] = __builtin_amdgcn_mfma_f32_16x16x32_bf16(
                    av, bv[n2][kk], acc[m][n2], 0, 0, 0);
        }
    #pragma unroll
    for (int m = 0; m < 2; ++m)
        #pragma unroll
        for (int n2 = 0; n2 < 2; ++n2)
            #pragma unroll
            for (int r = 0; r < 4; ++r)
                Hs[m * 16 + fh * 4 + r][w * 32 + n2 * 16 + fr] =
                    gelu_sig(acc[m][n2][r]);
    __syncthreads();

    // dots: wave w handles selections w*8..w*8+7
    for (int j = 0; j < 8; ++j) {
        int s = w * 8 + j;
        float2 hv = *(float2*)&Hs[s][l * 2];
        float2 xv = *(float2*)&xp[l * 2];
        float part = hv.x * xv.x + hv.y * xv.y;
        #pragma unroll
        for (int off = 32; off; off >>= 1) part += __shfl_xor(part, off, 64);
        if (l == 0)
            acts[s] = gelu_sig(part) * scores[n * HK + s];
    }
    __syncthreads();
    if (t < 128) {
        float a = 0.0f;
        #pragma unroll
        for (int s = 0; s < HK; ++s) a = fmaf(acts[s], Hs[s][t], a);
        accout[(size_t)n * DH + t] = a;
    }
}

// ---------------- Kernel D: out = (acc @ Wv)/4 via bf16 MFMA ----------------
// BM=64, BN=128, K=128 single-shot; grid (128, 8); M_rep=4, N_rep=2.
__global__ __launch_bounds__(256) void k_out(const float* __restrict__ acc,
                                             const float* __restrict__ Wv,
                                             float* __restrict__ out) {
    __shared__ unsigned short As[64][136];   // 64 rows x 128 k (+8 pad)
    const int t = threadIdx.x;
    const int w = t >> 6, l = t & 63;
    const int fr = l & 15, fh = l >> 4;
    const int row0 = blockIdx.x * 64;
    const int c0 = blockIdx.y * 128;
    const int ar = t >> 2, ac = (t & 3) * 32;    // 32 floats/thread (64x128)

    {
        const float* src = &acc[(size_t)(row0 + ar) * DH + ac];
        #pragma unroll
        for (int j = 0; j < 4; ++j) {
            float4 v0 = *(const float4*)&src[j * 8];
            float4 v1 = *(const float4*)&src[j * 8 + 4];
            *(bf16x8*)&As[ar][ac + j * 8] = pack8(v0, v1);
        }
    }
    bf16x8 bv[2][4];                         // [n][kk]
    #pragma unroll
    for (int n = 0; n < 2; ++n)
        #pragma unroll
        for (int kk = 0; kk < 4; ++kk)
            #pragma unroll
            for (int b = 0; b < 8; ++b)
                bv[n][kk][b] = (short)f2bf(
                    Wv[(size_t)(kk * 32 + fh * 8 + b) * DM + c0 + w * 32 + n * 16 + fr]);
    __syncthreads();

    f32x4 o[4][2] = {};
    #pragma unroll
    for (int kk = 0; kk < 4; ++kk)
        #pragma unroll
        for (int m = 0; m < 4; ++m) {
            bf16x8 av = *(bf16x8*)&As[m * 16 + fr][kk * 32 + fh * 8];
            #pragma unroll
            for (int n = 0; n < 2; ++n)
                o[m][n] = __builtin_amdgcn_mfma_f32_16x16x32_bf16(
                    av, bv[n][kk], o[m][n], 0, 0, 0);
        }
    #pragma unroll
    for (int m = 0; m < 4; ++m)
        #pragma unroll
        for (int n = 0; n < 2; ++n)
            #pragma unroll
            for (int r = 0; r < 4; ++r)
                out[(size_t)(row0 + m * 16 + fh * 4 + r) * DM + c0 + w * 32 + n * 16 + fr] =
                    o[m][n][r] * 0.25f;
}

extern "C" void kernel_launch(void* const* d_in, const int* in_sizes, int n_in,
                              void* d_out, int out_size, void* d_ws, size_t ws_size,
                              hipStream_t stream) {
    const float* x      = (const float*)d_in[0];
    const float* scores = (const float*)d_in[1];
    const int*   idx    = (const int*)d_in[2];
    const float* lat    = (const float*)d_in[3];
    const float* W1     = (const float*)d_in[4];
    const float* Wu     = (const float*)d_in[5];
    const float* Wv     = (const float*)d_in[6];
    float* out = (float*)d_out;

    float* xproj  = (float*)d_ws;                            // 8192*128 f32 (4 MB)
    float* accbuf = xproj + (size_t)NTOK * DH;               // 8192*128 f32 (4 MB)
    unsigned short* Wut = (unsigned short*)(accbuf + (size_t)NTOK * DH);  // 128x1024 bf16 (256 KB)
    unsigned short* W1T = Wut + (size_t)DH * DM;             // 128x64 bf16 (16 KB)

    k_prep<<<512 + 32, 256, 0, stream>>>(Wu, W1, Wut, W1T);
    k_xproj<<<dim3(NTOK / 32, 2), 256, 0, stream>>>(x, Wut, xproj);
    k_gather<<<NTOK, 256, 0, stream>>>(xproj, scores, idx, lat, W1T, accbuf);
    k_out<<<dim3(NTOK / 64, DM / 128), 256, 0, stream>>>(accbuf, Wv, out);
}

// Round 6
// 63.300 us; speedup vs baseline: 2.8851x; 1.2623x over previous
//
#include <hip/hip_runtime.h>
#include <hip/hip_bf16.h>

#define DM   1024
#define DH   128
#define DL   64
#define NTOK 8192
#define NEXP 65536
#define HK   32

typedef __attribute__((ext_vector_type(4))) float f32x4;
typedef __attribute__((ext_vector_type(8))) short bf16x8;

__device__ __forceinline__ float gelu_sig(float v) {
    return v / (1.0f + __expf(-1.702f * v));
}

__device__ __forceinline__ unsigned short f2bf(float f) {
    union { float f; unsigned u; } v; v.f = f;
    unsigned r = v.u + 0x7FFFu + ((v.u >> 16) & 1u);   // RNE
    return (unsigned short)(r >> 16);
}

__device__ __forceinline__ bf16x8 pack8(const float4& a, const float4& b) {
    bf16x8 r;
    r[0] = (short)f2bf(a.x); r[1] = (short)f2bf(a.y);
    r[2] = (short)f2bf(a.z); r[3] = (short)f2bf(a.w);
    r[4] = (short)f2bf(b.x); r[5] = (short)f2bf(b.y);
    r[6] = (short)f2bf(b.z); r[7] = (short)f2bf(b.w);
    return r;
}

// ---------------- Kernel P: transpose+convert Wu -> Wut[c][k], W1 -> W1T[c][k] ----------------
__global__ __launch_bounds__(256) void k_prep(const float* __restrict__ Wu,
                                              const float* __restrict__ W1,
                                              unsigned short* __restrict__ Wut,
                                              unsigned short* __restrict__ W1T) {
    const int b = blockIdx.x, t = threadIdx.x;
    if (b < 512) {                       // Wut: 128 x 1024
        const int i = b * 256 + t;
        const int c = i >> 10, k = i & 1023;
        Wut[i] = f2bf(Wu[k * DH + c]);
    } else {                             // W1T: 128 x 64
        const int j = (b - 512) * 256 + t;
        const int c = j >> 6, k = j & 63;
        W1T[j] = f2bf(W1[k * DH + c]);
    }
}

// ---------------- Kernel A: xproj = x @ Wu via bf16 MFMA ----------------
// grid (NTOK/32, 2): 32 rows x 64 cols per block; 4 waves, each 16 cols (N_rep=1, M_rep=2).
__global__ __launch_bounds__(256) void k_xproj(const float* __restrict__ x,
                                               const unsigned short* __restrict__ Wut,
                                               float* __restrict__ xproj) {
    __shared__ unsigned short As[32][72];    // 32 rows x 64 k (+8 pad)
    __shared__ unsigned short Bs[64][72];    // 64 cols x 64 k (+8 pad)
    const int t = threadIdx.x;
    const int w = t >> 6, l = t & 63;
    const int fr = l & 15, fh = l >> 4;
    const int row0 = blockIdx.x * 32;
    const int cb = blockIdx.y * 64;
    const int ar = t >> 3, ac = (t & 7) * 8;     // A: 8 floats/thread (32x64)
    const int bc = t >> 2, bk = (t & 3) * 16;    // B: 16 bf16/thread (64x64)

    f32x4 acc[2] = {};
    float4 a0, a1; bf16x8 b0, b1;

    a0 = *(const float4*)&x[(size_t)(row0 + ar) * DM + ac];
    a1 = *(const float4*)&x[(size_t)(row0 + ar) * DM + ac + 4];
    b0 = *(const bf16x8*)&Wut[(size_t)(cb + bc) * DM + bk];
    b1 = *(const bf16x8*)&Wut[(size_t)(cb + bc) * DM + bk + 8];

    for (int it = 0; it < DM / 64; ++it) {
        if (it) __syncthreads();
        *(bf16x8*)&As[ar][ac]     = pack8(a0, a1);
        *(bf16x8*)&Bs[bc][bk]     = b0;
        *(bf16x8*)&Bs[bc][bk + 8] = b1;
        __syncthreads();
        if (it < DM / 64 - 1) {
            const int kc = (it + 1) * 64;
            a0 = *(const float4*)&x[(size_t)(row0 + ar) * DM + kc + ac];
            a1 = *(const float4*)&x[(size_t)(row0 + ar) * DM + kc + ac + 4];
            b0 = *(const bf16x8*)&Wut[(size_t)(cb + bc) * DM + kc + bk];
            b1 = *(const bf16x8*)&Wut[(size_t)(cb + bc) * DM + kc + bk + 8];
        }
        #pragma unroll
        for (int kk = 0; kk < 2; ++kk) {
            bf16x8 bv = *(bf16x8*)&Bs[w * 16 + fr][kk * 32 + fh * 8];
            #pragma unroll
            for (int m = 0; m < 2; ++m) {
                bf16x8 av = *(bf16x8*)&As[m * 16 + fr][kk * 32 + fh * 8];
                acc[m] = __builtin_amdgcn_mfma_f32_16x16x32_bf16(av, bv, acc[m], 0, 0, 0);
            }
        }
    }
    #pragma unroll
    for (int m = 0; m < 2; ++m)
        #pragma unroll
        for (int r = 0; r < 4; ++r)
            xproj[(size_t)(row0 + m * 16 + fh * 4 + r) * DH + cb + w * 16 + fr] =
                acc[m][r];
}

// ---------------- Kernel C: gather lat + h=gelu(lat@W1) MFMA + dot + act + accumulate ----------------
__global__ __launch_bounds__(256) void k_gather(const float* __restrict__ xproj,
                                                const float* __restrict__ scores,
                                                const int* __restrict__ idx,
                                                const float* __restrict__ lat,
                                                const unsigned short* __restrict__ W1T,
                                                float* __restrict__ accout) {
    __shared__ unsigned short As[HK][72];    // 32 sel x 64 latent bf16 (+8 pad)
    __shared__ float Hs[HK][132];            // 32 sel x 128 hidden fp32 (+4 pad)
    __shared__ float xp[132];
    __shared__ float acts[HK];
    __shared__ float psum[DH];
    const int n = blockIdx.x;
    const int t = threadIdx.x;
    const int w = t >> 6, l = t & 63;
    const int fr = l & 15, fh = l >> 4;

    // Phase A: gather lat rows -> bf16 LDS; xp -> LDS; B-frags from W1T
    {
        const int row = t >> 3, c = (t & 7) * 8;
        const int e = idx[n * HK + row];         // 8-way broadcast within cacheline
        const float* src = &lat[(size_t)e * DL + c];
        float4 v0 = *(const float4*)&src[0], v1 = *(const float4*)&src[4];
        *(bf16x8*)&As[row][c] = pack8(v0, v1);
    }
    if (t < 128) xp[t] = xproj[(size_t)n * DH + t];
    bf16x8 bv[2][2];                          // [n2][kk]
    #pragma unroll
    for (int n2 = 0; n2 < 2; ++n2)
        #pragma unroll
        for (int kk = 0; kk < 2; ++kk)
            bv[n2][kk] = *(const bf16x8*)
                &W1T[(size_t)(w * 32 + n2 * 16 + fr) * DL + kk * 32 + fh * 8];
    __syncthreads();

    // Phase B: h = gelu(lat @ W1): M=32, N=128, K=64; wave w -> cols w*32
    f32x4 acc[2][2] = {};
    #pragma unroll
    for (int kk = 0; kk < 2; ++kk)
        #pragma unroll
        for (int m = 0; m < 2; ++m) {
            bf16x8 av = *(bf16x8*)&As[m * 16 + fr][kk * 32 + fh * 8];
            #pragma unroll
            for (int n2 = 0; n2 < 2; ++n2)
                acc[m][n2] = __builtin_amdgcn_mfma_f32_16x16x32_bf16(
                    av, bv[n2][kk], acc[m][n2], 0, 0, 0);
        }
    #pragma unroll
    for (int m = 0; m < 2; ++m)
        #pragma unroll
        for (int n2 = 0; n2 < 2; ++n2)
            #pragma unroll
            for (int r = 0; r < 4; ++r)
                Hs[m * 16 + fh * 4 + r][w * 32 + n2 * 16 + fr] =
                    gelu_sig(acc[m][n2][r]);
    __syncthreads();

    // Phase C: dots. s = t>>3 (32 sels), j = t&7 owns f = j*16..+15.
    {
        const int s = t >> 3, j = t & 7, f0 = j * 16;
        float part = 0.0f;
        #pragma unroll
        for (int k = 0; k < 4; ++k) {
            float4 hv = *(float4*)&Hs[s][f0 + k * 4];
            float4 xv = *(float4*)&xp[f0 + k * 4];
            part = fmaf(hv.x, xv.x, part);
            part = fmaf(hv.y, xv.y, part);
            part = fmaf(hv.z, xv.z, part);
            part = fmaf(hv.w, xv.w, part);
        }
        part += __shfl_xor(part, 1, 64);
        part += __shfl_xor(part, 2, 64);
        part += __shfl_xor(part, 4, 64);
        float a = gelu_sig(part) * scores[n * HK + s];
        if (j == 0) acts[s] = a;
    }
    __syncthreads();

    // Phase D: accout[f] = sum_s acts[s]*Hs[s][f]; f = t&127, half hh = t>>7.
    {
        const int f = t & 127, hh = t >> 7;
        float a = 0.0f;
        #pragma unroll
        for (int s8 = 0; s8 < 16; ++s8) {
            int s = hh * 16 + s8;
            a = fmaf(acts[s], Hs[s][f], a);
        }
        if (hh) psum[f] = a;
        __syncthreads();
        if (!hh) accout[(size_t)n * DH + f] = a + psum[f];
    }
}

// ---------------- Kernel D: out = (acc @ Wv)/4 via bf16 MFMA ----------------
// BM=64, BN=128, K=128 single-shot; grid (128, 8); M_rep=4, N_rep=2.
__global__ __launch_bounds__(256) void k_out(const float* __restrict__ acc,
                                             const float* __restrict__ Wv,
                                             float* __restrict__ out) {
    __shared__ unsigned short As[64][136];   // 64 rows x 128 k (+8 pad)
    const int t = threadIdx.x;
    const int w = t >> 6, l = t & 63;
    const int fr = l & 15, fh = l >> 4;
    const int row0 = blockIdx.x * 64;
    const int c0 = blockIdx.y * 128;
    const int ar = t >> 2, ac = (t & 3) * 32;    // 32 floats/thread (64x128)

    {
        const float* src = &acc[(size_t)(row0 + ar) * DH + ac];
        #pragma unroll
        for (int j = 0; j < 4; ++j) {
            float4 v0 = *(const float4*)&src[j * 8];
            float4 v1 = *(const float4*)&src[j * 8 + 4];
            *(bf16x8*)&As[ar][ac + j * 8] = pack8(v0, v1);
        }
    }
    bf16x8 bv[2][4];                         // [n][kk]
    #pragma unroll
    for (int n = 0; n < 2; ++n)
        #pragma unroll
        for (int kk = 0; kk < 4; ++kk)
            #pragma unroll
            for (int b = 0; b < 8; ++b)
                bv[n][kk][b] = (short)f2bf(
                    Wv[(size_t)(kk * 32 + fh * 8 + b) * DM + c0 + w * 32 + n * 16 + fr]);
    __syncthreads();

    f32x4 o[4][2] = {};
    #pragma unroll
    for (int kk = 0; kk < 4; ++kk)
        #pragma unroll
        for (int m = 0; m < 4; ++m) {
            bf16x8 av = *(bf16x8*)&As[m * 16 + fr][kk * 32 + fh * 8];
            #pragma unroll
            for (int n = 0; n < 2; ++n)
                o[m][n] = __builtin_amdgcn_mfma_f32_16x16x32_bf16(
                    av, bv[n][kk], o[m][n], 0, 0, 0);
        }
    #pragma unroll
    for (int m = 0; m < 4; ++m)
        #pragma unroll
        for (int n = 0; n < 2; ++n)
            #pragma unroll
            for (int r = 0; r < 4; ++r)
                out[(size_t)(row0 + m * 16 + fh * 4 + r) * DM + c0 + w * 32 + n * 16 + fr] =
                    o[m][n][r] * 0.25f;
}

extern "C" void kernel_launch(void* const* d_in, const int* in_sizes, int n_in,
                              void* d_out, int out_size, void* d_ws, size_t ws_size,
                              hipStream_t stream) {
    const float* x      = (const float*)d_in[0];
    const float* scores = (const float*)d_in[1];
    const int*   idx    = (const int*)d_in[2];
    const float* lat    = (const float*)d_in[3];
    const float* W1     = (const float*)d_in[4];
    const float* Wu     = (const float*)d_in[5];
    const float* Wv     = (const float*)d_in[6];
    float* out = (float*)d_out;

    float* xproj  = (float*)d_ws;                            // 8192*128 f32 (4 MB)
    float* accbuf = xproj + (size_t)NTOK * DH;               // 8192*128 f32 (4 MB)
    unsigned short* Wut = (unsigned short*)(accbuf + (size_t)NTOK * DH);  // 128x1024 bf16 (256 KB)
    unsigned short* W1T = Wut + (size_t)DH * DM;             // 128x64 bf16 (16 KB)

    k_prep<<<512 + 32, 256, 0, stream>>>(Wu, W1, Wut, W1T);
    k_xproj<<<dim3(NTOK / 32, 2), 256, 0, stream>>>(x, Wut, xproj);
    k_gather<<<NTOK, 256, 0, stream>>>(xproj, scores, idx, lat, W1T, accbuf);
    k_out<<<dim3(NTOK / 64, DM / 128), 256, 0, stream>>>(accbuf, Wv, out);
}

// Round 7
// 62.158 us; speedup vs baseline: 2.9381x; 1.0184x over previous
//
#include <hip/hip_runtime.h>
#include <hip/hip_bf16.h>

#define DM   1024
#define DH   128
#define DL   64
#define NTOK 8192
#define NEXP 65536
#define HK   32

typedef __attribute__((ext_vector_type(4))) float f32x4;
typedef __attribute__((ext_vector_type(8))) short bf16x8;

__device__ __forceinline__ float gelu_sig(float v) {
    // v * sigmoid(1.702 v) with HW rcp (<=1 ulp) instead of precise div:
    // saves ~10 VALU instr per call vs v_div_scale/fmas/fixup expansion.
    return v * __builtin_amdgcn_rcpf(1.0f + __expf(-1.702f * v));
}

__device__ __forceinline__ unsigned short f2bf(float f) {
    union { float f; unsigned u; } v; v.f = f;
    unsigned r = v.u + 0x7FFFu + ((v.u >> 16) & 1u);   // RNE
    return (unsigned short)(r >> 16);
}

__device__ __forceinline__ bf16x8 pack8(const float4& a, const float4& b) {
    bf16x8 r;
    r[0] = (short)f2bf(a.x); r[1] = (short)f2bf(a.y);
    r[2] = (short)f2bf(a.z); r[3] = (short)f2bf(a.w);
    r[4] = (short)f2bf(b.x); r[5] = (short)f2bf(b.y);
    r[6] = (short)f2bf(b.z); r[7] = (short)f2bf(b.w);
    return r;
}

// ---------------- Kernel P: transpose+convert Wu -> Wut[c][k], W1 -> W1T[c][k] ----------------
__global__ __launch_bounds__(256) void k_prep(const float* __restrict__ Wu,
                                              const float* __restrict__ W1,
                                              unsigned short* __restrict__ Wut,
                                              unsigned short* __restrict__ W1T) {
    const int b = blockIdx.x, t = threadIdx.x;
    if (b < 512) {                       // Wut: 128 x 1024
        const int i = b * 256 + t;
        const int c = i >> 10, k = i & 1023;
        Wut[i] = f2bf(Wu[k * DH + c]);
    } else {                             // W1T: 128 x 64
        const int j = (b - 512) * 256 + t;
        const int c = j >> 6, k = j & 63;
        W1T[j] = f2bf(W1[k * DH + c]);
    }
}

// ---------------- Kernel A: xproj = x @ Wu via bf16 MFMA ----------------
// grid (NTOK/32, 2): 32 rows x 64 cols per block; 4 waves, each 16 cols (N_rep=1, M_rep=2).
__global__ __launch_bounds__(256) void k_xproj(const float* __restrict__ x,
                                               const unsigned short* __restrict__ Wut,
                                               float* __restrict__ xproj) {
    __shared__ unsigned short As[32][72];    // 32 rows x 64 k (+8 pad)
    __shared__ unsigned short Bs[64][72];    // 64 cols x 64 k (+8 pad)
    const int t = threadIdx.x;
    const int w = t >> 6, l = t & 63;
    const int fr = l & 15, fh = l >> 4;
    const int row0 = blockIdx.x * 32;
    const int cb = blockIdx.y * 64;
    const int ar = t >> 3, ac = (t & 7) * 8;     // A: 8 floats/thread (32x64)
    const int bc = t >> 2, bk = (t & 3) * 16;    // B: 16 bf16/thread (64x64)

    f32x4 acc[2] = {};
    float4 a0, a1; bf16x8 b0, b1;

    a0 = *(const float4*)&x[(size_t)(row0 + ar) * DM + ac];
    a1 = *(const float4*)&x[(size_t)(row0 + ar) * DM + ac + 4];
    b0 = *(const bf16x8*)&Wut[(size_t)(cb + bc) * DM + bk];
    b1 = *(const bf16x8*)&Wut[(size_t)(cb + bc) * DM + bk + 8];

    for (int it = 0; it < DM / 64; ++it) {
        if (it) __syncthreads();
        *(bf16x8*)&As[ar][ac]     = pack8(a0, a1);
        *(bf16x8*)&Bs[bc][bk]     = b0;
        *(bf16x8*)&Bs[bc][bk + 8] = b1;
        __syncthreads();
        if (it < DM / 64 - 1) {
            const int kc = (it + 1) * 64;
            a0 = *(const float4*)&x[(size_t)(row0 + ar) * DM + kc + ac];
            a1 = *(const float4*)&x[(size_t)(row0 + ar) * DM + kc + ac + 4];
            b0 = *(const bf16x8*)&Wut[(size_t)(cb + bc) * DM + kc + bk];
            b1 = *(const bf16x8*)&Wut[(size_t)(cb + bc) * DM + kc + bk + 8];
        }
        #pragma unroll
        for (int kk = 0; kk < 2; ++kk) {
            bf16x8 bv = *(bf16x8*)&Bs[w * 16 + fr][kk * 32 + fh * 8];
            #pragma unroll
            for (int m = 0; m < 2; ++m) {
                bf16x8 av = *(bf16x8*)&As[m * 16 + fr][kk * 32 + fh * 8];
                acc[m] = __builtin_amdgcn_mfma_f32_16x16x32_bf16(av, bv, acc[m], 0, 0, 0);
            }
        }
    }
    #pragma unroll
    for (int m = 0; m < 2; ++m)
        #pragma unroll
        for (int r = 0; r < 4; ++r)
            xproj[(size_t)(row0 + m * 16 + fh * 4 + r) * DH + cb + w * 16 + fr] =
                acc[m][r];
}

// ---------------- Kernel C: gather lat + h=gelu(lat@W1) MFMA + dot + act + accumulate ----------------
__global__ __launch_bounds__(256) void k_gather(const float* __restrict__ xproj,
                                                const float* __restrict__ scores,
                                                const int* __restrict__ idx,
                                                const float* __restrict__ lat,
                                                const unsigned short* __restrict__ W1T,
                                                float* __restrict__ accout) {
    __shared__ unsigned short As[HK][72];    // 32 sel x 64 latent bf16 (+8 pad)
    __shared__ float Hs[HK][132];            // 32 sel x 128 hidden fp32 (+4 pad)
    __shared__ float xp[132];
    __shared__ float acts[HK];
    __shared__ float psum[DH];
    const int n = blockIdx.x;
    const int t = threadIdx.x;
    const int w = t >> 6, l = t & 63;
    const int fr = l & 15, fh = l >> 4;

    // Phase A: gather lat rows -> bf16 LDS; xp -> LDS; B-frags from W1T
    {
        const int row = t >> 3, c = (t & 7) * 8;
        const int e = idx[n * HK + row];         // 8-way broadcast within cacheline
        const float* src = &lat[(size_t)e * DL + c];
        float4 v0 = *(const float4*)&src[0], v1 = *(const float4*)&src[4];
        *(bf16x8*)&As[row][c] = pack8(v0, v1);
    }
    if (t < 128) xp[t] = xproj[(size_t)n * DH + t];
    bf16x8 bv[2][2];                          // [n2][kk]
    #pragma unroll
    for (int n2 = 0; n2 < 2; ++n2)
        #pragma unroll
        for (int kk = 0; kk < 2; ++kk)
            bv[n2][kk] = *(const bf16x8*)
                &W1T[(size_t)(w * 32 + n2 * 16 + fr) * DL + kk * 32 + fh * 8];
    __syncthreads();

    // Phase B: h = gelu(lat @ W1): M=32, N=128, K=64; wave w -> cols w*32
    f32x4 acc[2][2] = {};
    #pragma unroll
    for (int kk = 0; kk < 2; ++kk)
        #pragma unroll
        for (int m = 0; m < 2; ++m) {
            bf16x8 av = *(bf16x8*)&As[m * 16 + fr][kk * 32 + fh * 8];
            #pragma unroll
            for (int n2 = 0; n2 < 2; ++n2)
                acc[m][n2] = __builtin_amdgcn_mfma_f32_16x16x32_bf16(
                    av, bv[n2][kk], acc[m][n2], 0, 0, 0);
        }
    #pragma unroll
    for (int m = 0; m < 2; ++m)
        #pragma unroll
        for (int n2 = 0; n2 < 2; ++n2)
            #pragma unroll
            for (int r = 0; r < 4; ++r)
                Hs[m * 16 + fh * 4 + r][w * 32 + n2 * 16 + fr] =
                    gelu_sig(acc[m][n2][r]);
    __syncthreads();

    // Phase C: dots. s = t>>3 (32 sels), j = t&7 owns f = j*16..+15.
    {
        const int s = t >> 3, j = t & 7, f0 = j * 16;
        float part = 0.0f;
        #pragma unroll
        for (int k = 0; k < 4; ++k) {
            float4 hv = *(float4*)&Hs[s][f0 + k * 4];
            float4 xv = *(float4*)&xp[f0 + k * 4];
            part = fmaf(hv.x, xv.x, part);
            part = fmaf(hv.y, xv.y, part);
            part = fmaf(hv.z, xv.z, part);
            part = fmaf(hv.w, xv.w, part);
        }
        part += __shfl_xor(part, 1, 64);
        part += __shfl_xor(part, 2, 64);
        part += __shfl_xor(part, 4, 64);
        float a = gelu_sig(part) * scores[n * HK + s];
        if (j == 0) acts[s] = a;
    }
    __syncthreads();

    // Phase D: accout[f] = sum_s acts[s]*Hs[s][f]; f = t&127, half hh = t>>7.
    {
        const int f = t & 127, hh = t >> 7;
        float a = 0.0f;
        #pragma unroll
        for (int s8 = 0; s8 < 16; ++s8) {
            int s = hh * 16 + s8;
            a = fmaf(acts[s], Hs[s][f], a);
        }
        if (hh) psum[f] = a;
        __syncthreads();
        if (!hh) accout[(size_t)n * DH + f] = a + psum[f];
    }
}

// ---------------- Kernel D: out = (acc @ Wv)/4 via bf16 MFMA ----------------
// BM=64, BN=128, K=128 single-shot; grid (128, 8); M_rep=4, N_rep=2.
__global__ __launch_bounds__(256) void k_out(const float* __restrict__ acc,
                                             const float* __restrict__ Wv,
                                             float* __restrict__ out) {
    __shared__ unsigned short As[64][136];   // 64 rows x 128 k (+8 pad)
    const int t = threadIdx.x;
    const int w = t >> 6, l = t & 63;
    const int fr = l & 15, fh = l >> 4;
    const int row0 = blockIdx.x * 64;
    const int c0 = blockIdx.y * 128;
    const int ar = t >> 2, ac = (t & 3) * 32;    // 32 floats/thread (64x128)

    {
        const float* src = &acc[(size_t)(row0 + ar) * DH + ac];
        #pragma unroll
        for (int j = 0; j < 4; ++j) {
            float4 v0 = *(const float4*)&src[j * 8];
            float4 v1 = *(const float4*)&src[j * 8 + 4];
            *(bf16x8*)&As[ar][ac + j * 8] = pack8(v0, v1);
        }
    }
    bf16x8 bv[2][4];                         // [n][kk]
    #pragma unroll
    for (int n = 0; n < 2; ++n)
        #pragma unroll
        for (int kk = 0; kk < 4; ++kk)
            #pragma unroll
            for (int b = 0; b < 8; ++b)
                bv[n][kk][b] = (short)f2bf(
                    Wv[(size_t)(kk * 32 + fh * 8 + b) * DM + c0 + w * 32 + n * 16 + fr]);
    __syncthreads();

    f32x4 o[4][2] = {};
    #pragma unroll
    for (int kk = 0; kk < 4; ++kk)
        #pragma unroll
        for (int m = 0; m < 4; ++m) {
            bf16x8 av = *(bf16x8*)&As[m * 16 + fr][kk * 32 + fh * 8];
            #pragma unroll
            for (int n = 0; n < 2; ++n)
                o[m][n] = __builtin_amdgcn_mfma_f32_16x16x32_bf16(
                    av, bv[n][kk], o[m][n], 0, 0, 0);
        }
    #pragma unroll
    for (int m = 0; m < 4; ++m)
        #pragma unroll
        for (int n = 0; n < 2; ++n)
            #pragma unroll
            for (int r = 0; r < 4; ++r)
                out[(size_t)(row0 + m * 16 + fh * 4 + r) * DM + c0 + w * 32 + n * 16 + fr] =
                    o[m][n][r] * 0.25f;
}

extern "C" void kernel_launch(void* const* d_in, const int* in_sizes, int n_in,
                              void* d_out, int out_size, void* d_ws, size_t ws_size,
                              hipStream_t stream) {
    const float* x      = (const float*)d_in[0];
    const float* scores = (const float*)d_in[1];
    const int*   idx    = (const int*)d_in[2];
    const float* lat    = (const float*)d_in[3];
    const float* W1     = (const float*)d_in[4];
    const float* Wu     = (const float*)d_in[5];
    const float* Wv     = (const float*)d_in[6];
    float* out = (float*)d_out;

    float* xproj  = (float*)d_ws;                            // 8192*128 f32 (4 MB)
    float* accbuf = xproj + (size_t)NTOK * DH;               // 8192*128 f32 (4 MB)
    unsigned short* Wut = (unsigned short*)(accbuf + (size_t)NTOK * DH);  // 128x1024 bf16 (256 KB)
    unsigned short* W1T = Wut + (size_t)DH * DM;             // 128x64 bf16 (16 KB)

    k_prep<<<512 + 32, 256, 0, stream>>>(Wu, W1, Wut, W1T);
    k_xproj<<<dim3(NTOK / 32, 2), 256, 0, stream>>>(x, Wut, xproj);
    k_gather<<<NTOK, 256, 0, stream>>>(xproj, scores, idx, lat, W1T, accbuf);
    k_out<<<dim3(NTOK / 64, DM / 128), 256, 0, stream>>>(accbuf, Wv, out);
}